// Round 14
// baseline (120.632 us; speedup 1.0000x reference)
//
#include <hip/hip_runtime.h>

#define BB 8
#define CC 256

typedef __attribute__((ext_vector_type(8))) short short8;
typedef __attribute__((ext_vector_type(4))) float f32x4;

__device__ __forceinline__ float silu_f(float v){
  float e = exp2f(v * -1.44269504088896340736f);
  return v * __builtin_amdgcn_rcpf(1.f + e);
}
__device__ __forceinline__ float hsig_f(float v){ return fminf(fmaxf(v + 3.f, 0.f), 6.f) * (1.f/6.f); }
__device__ __forceinline__ unsigned short f2bf(float f){
  unsigned int u = __float_as_uint(f);
  unsigned int r = u + 0x7fffu + ((u >> 16) & 1u);
  return (unsigned short)(r >> 16);
}
__device__ __forceinline__ float bf2f(unsigned short u){ return __uint_as_float(((unsigned int)u)<<16); }

// ================= depthwise: merged-input multi-conv, 32-ch slabs (+ prep blocks) =================
struct DwG {
  const float* in;
  const float* w1a; const float* b1a; unsigned short* o1a;
  const float* w1b; const float* b1b; unsigned short* o1b;
  const float* w2;  const float* b2;  unsigned short* o2;
  int blocks;
};
struct DwPrepArgs {
  DwG g[3];
  const float* pw_w; unsigned short* wbf;
  float* wtab32; float* wtab16; float* zeros;
};

template<int C> struct RowT { float v[C+2]; };

template<int C>
__device__ __forceinline__ void loadRow(const float* rp, bool valid, bool hasL, bool hasR, RowT<C>& r){
  if (!valid){
    #pragma unroll
    for (int i=0;i<C+2;++i) r.v[i]=0.f;
    return;
  }
  r.v[0] = hasL ? rp[-1] : 0.f;
  if constexpr (C >= 4){
    #pragma unroll
    for (int q=0;q<C/4;++q){
      float4 f = *(const float4*)(rp + q*4);
      r.v[1+q*4+0]=f.x; r.v[1+q*4+1]=f.y; r.v[1+q*4+2]=f.z; r.v[1+q*4+3]=f.w;
    }
  } else {
    #pragma unroll
    for (int i=0;i<C;++i) r.v[1+i] = rp[i];
  }
  r.v[C+1] = hasR ? rp[C] : 0.f;
}

template<int C>
__device__ __forceinline__ void conv1row(const RowT<C>& ra, const RowT<C>& rb, const RowT<C>& rc,
                                         const float* w9, float bias, unsigned short* dst){
  #pragma unroll
  for (int j=0;j<C;++j){
    float a = bias
      + w9[0]*ra.v[j] + w9[1]*ra.v[j+1] + w9[2]*ra.v[j+2]
      + w9[3]*rb.v[j] + w9[4]*rb.v[j+1] + w9[5]*rb.v[j+2]
      + w9[6]*rc.v[j] + w9[7]*rc.v[j+1] + w9[8]*rc.v[j+2];
    dst[j] = f2bf(silu_f(a));
  }
}

template<int C>
__device__ __forceinline__ void conv1rowS2(const RowT<C>& ra, const RowT<C>& rb, const RowT<C>& rc,
                                           const float* w9, float bias, unsigned short* dst){
  #pragma unroll
  for (int jj=0;jj<C/2;++jj){
    float a = bias
      + w9[0]*ra.v[2*jj] + w9[1]*ra.v[2*jj+1] + w9[2]*ra.v[2*jj+2]
      + w9[3]*rb.v[2*jj] + w9[4]*rb.v[2*jj+1] + w9[5]*rb.v[2*jj+2]
      + w9[6]*rc.v[2*jj] + w9[7]*rc.v[2*jj+1] + w9[8]*rc.v[2*jj+2];
    dst[jj] = f2bf(silu_f(a));
  }
}

// gather LDS (padded [32ch][RO][P]) -> fragment-order global (16B chunks)
template<int LWO, int RO, int P>
__device__ __forceinline__ void writeFrag32(const unsigned short* sbuf, unsigned short* outBase,
                                            int cg, int tid){
  constexpr int WO = 1<<LWO;
  constexpr int total = RO*WO*4;
  constexpr int iters = (total + 255)/256;
  #pragma unroll
  for (int h=0; h<iters; ++h){
    int jc = h*256 + tid;
    if (jc < total){
      int lp = jc & 15, c4 = (jc>>4)&3, pt = jc>>6;
      int pl = pt*16 + lp;
      int rowl = pl >> LWO, col = pl & (WO-1);
      const unsigned short* sp = sbuf + ((size_t)(c4*8)*RO + rowl)*P + col;
      unsigned int e0 = sp[0*RO*P], e1 = sp[1*RO*P], e2 = sp[2*RO*P], e3 = sp[3*RO*P];
      unsigned int e4 = sp[4*RO*P], e5 = sp[5*RO*P], e6 = sp[6*RO*P], e7 = sp[7*RO*P];
      uint4 v;
      v.x = e0 | (e1<<16); v.y = e2 | (e3<<16); v.z = e4 | (e5<<16); v.w = e6 | (e7<<16);
      size_t off = (size_t)pt*4096 + (size_t)cg*512 + c4*128 + lp*8;
      *(uint4*)(outBase + off) = v;
    }
  }
}

template<int LW, int R, int N1, bool S2>
__device__ void dw_group32(const DwG& g, int bid, unsigned short* sm){
  constexpr int W = 1<<LW;
  constexpr int C = W/8;
  constexpr int P1 = W + 4;
  constexpr int P2 = W/2 + 4;
  const int tid = threadIdx.x;
  const int ch = tid >> 3, ct = tid & 7, c0 = ct*C;
  const int cg = bid & 7;
  int rest = bid >> 3;
  const int NR = W / R;
  const int b = rest / NR, rb = rest % NR, r0 = rb * R;

  const float* ip = g.in + ((size_t)b*CC + cg*32 + ch) * (W*W);
  const int chg = cg*32 + ch;
  float w1a[9], w1b[9], w2[9];
  float bs1a = g.b1a[chg], bs1b = 0.f, bs2 = 0.f;
  #pragma unroll
  for (int k=0;k<9;++k) w1a[k] = g.w1a[chg*9+k];
  if (N1==2){
    bs1b = g.b1b[chg];
    #pragma unroll
    for (int k=0;k<9;++k) w1b[k] = g.w1b[chg*9+k];
  }
  if (S2){
    bs2 = g.b2[chg];
    #pragma unroll
    for (int k=0;k<9;++k) w2[k] = g.w2[chg*9+k];
  }

  unsigned short* s1a = sm;
  unsigned short* s1b = sm + (size_t)32*R*P1;
  unsigned short* s2b = sm + (size_t)N1*32*R*P1;

  RowT<C> RA, RB, RC;
  const bool hasL = (c0 > 0), hasR = (c0 + C < W);
  {
    int ry = r0-1; loadRow<C>(ip + ry*W + c0, ry>=0 && ry<W, hasL, hasR, RA);
    ry = r0;       loadRow<C>(ip + ry*W + c0, ry>=0 && ry<W, hasL, hasR, RB);
    ry = r0+1;     loadRow<C>(ip + ry*W + c0, ry>=0 && ry<W, hasL, hasR, RC);
  }
  #pragma unroll
  for (int y=0; y<R; ++y){
    const RowT<C>& ra  = (y%3==0)?RA:((y%3==1)?RB:RC);
    const RowT<C>& rbm = (y%3==0)?RB:((y%3==1)?RC:RA);
    const RowT<C>& rc  = (y%3==0)?RC:((y%3==1)?RA:RB);
    conv1row<C>(ra, rbm, rc, w1a, bs1a, s1a + ((size_t)ch*R + y)*P1 + c0);
    if (N1==2) conv1row<C>(ra, rbm, rc, w1b, bs1b, s1b + ((size_t)ch*R + y)*P1 + c0);
    if (S2 && (y%2==0))
      conv1rowS2<C>(ra, rbm, rc, w2, bs2, s2b + ((size_t)ch*(R/2) + y/2)*P2 + c0/2);
    if (y < R-1){
      RowT<C>& dst = (y%3==0)?RA:((y%3==1)?RB:RC);
      int ry = r0 + y + 2;
      loadRow<C>(ip + ry*W + c0, ry>=0 && ry<W, hasL, hasR, dst);
    }
  }
  __syncthreads();

  {
    unsigned short* ob = g.o1a + ((size_t)b*(W*W) + r0*W)*256;
    writeFrag32<LW, R, P1>(s1a, ob, cg, tid);
  }
  if (N1==2){
    unsigned short* ob = g.o1b + ((size_t)b*(W*W) + r0*W)*256;
    writeFrag32<LW, R, P1>(s1b, ob, cg, tid);
  }
  if (S2){
    unsigned short* ob = g.o2 + ((size_t)b*((W/2)*(W/2)) + (r0/2)*(W/2))*256;
    writeFrag32<LW-1, R/2, P2>(s2b, ob, cg, tid);
  }
}

__device__ float accw(int yi, int Ho, int Hi){
  float sc = (float)(Hi-1)/(float)(Ho-1);
  float a = 0.f;
  for (int yo=0; yo<Ho; ++yo){
    float ys = yo*sc; int y0 = (int)ys; float w = ys - y0; int y1 = min(y0+1, Hi-1);
    if (y0==yi) a += 1.f - w;
    if (y1==yi) a += w;
  }
  return a;
}

__global__ __launch_bounds__(256) void dw_kernel(DwPrepArgs A){
  __shared__ unsigned short smem[11008];
  int bid = blockIdx.x;
  if (bid < 1664){
    int gi = 0;
    while (bid >= A.g[gi].blocks){ bid -= A.g[gi].blocks; ++gi; }
    if (gi == 0)      dw_group32<6,4,1,true >(A.g[0], bid, smem);
    else if (gi == 1) dw_group32<5,4,2,true >(A.g[1], bid, smem);
    else              dw_group32<4,8,2,false>(A.g[2], bid, smem);
    return;
  }
  int idx = (bid - 1664)*256 + threadIdx.x;
  const int T = 5*65536;
  if (idx < T){
    const int widx[5] = {1,4,5,7,8};
    int slot = idx >> 16, r = idx & 65535;
    int ct = r>>12, s=(r>>9)&7, g=(r>>7)&3, lr=(r>>3)&15, e=r&7;
    int co = ct*16+lr, k = s*32+g*8+e;
    A.wbf[idx] = f2bf(A.pw_w[(size_t)widx[slot]*65536 + co*256 + k]);
  } else if (idx < T+1024){
    int p = idx - T; int y=p>>5, x=p&31;
    A.wtab32[p] = accw(y,64,32)*accw(x,64,32);
  } else if (idx < T+1280){
    int p = idx - T - 1024; int y=p>>4, x=p&15;
    A.wtab16[p] = accw(y,32,16)*accw(x,32,16);
  } else if (idx < T+1280+20480){
    A.zeros[idx - T - 1280] = 0.f;
  }
}

// ---------------- pointwise 1x1 via bf16 MFMA (sw-pipelined main loop) ----------------
struct PwT { const unsigned short* in; const unsigned short* w; const float* bias;
             unsigned short* out; const float* wtab; float norm; int HW; int blocks; int slot; };
struct PwArgs { PwT t[7]; };

__global__ __launch_bounds__(256) void pw_kernel(PwArgs A, float* __restrict__ means){
  __shared__ unsigned short cs[32*136];
  __shared__ float smean[64];
  int bid = blockIdx.x; int ti = 0;
  while (bid >= A.t[ti].blocks){ bid -= A.t[ti].blocks; ++ti; }
  PwT t = A.t[ti];
  const int nbx = t.HW >> 7;
  const int b  = bid / (nbx*4);
  const int r  = bid % (nbx*4);
  const int co0 = (r & 3) * 64;
  const int p0  = (r >> 2) * 128;
  const int tid = threadIdx.x;
  const int wid = tid >> 6, l = tid & 63;
  const int wm = wid >> 1, wn = wid & 1;
  const int lr = l & 15, g = l >> 4;

  if (tid < 64) smean[tid] = 0.f;

  const unsigned short* wbase = t.w + ((co0 + wm*32) >> 4)*4096 + l*8;
  const unsigned short* bbase = t.in + (size_t)b*t.HW*256 + ((p0 + wn*64) >> 4)*4096 + l*8;

  f32x4 acc[2][4] = {};
  // explicit 1-deep software pipeline: named current/next operand sets
  short8 a0 = *(const short8*)(wbase + 0*4096);
  short8 a1 = *(const short8*)(wbase + 1*4096);
  short8 b0 = *(const short8*)(bbase + 0*4096);
  short8 b1 = *(const short8*)(bbase + 1*4096);
  short8 b2 = *(const short8*)(bbase + 2*4096);
  short8 b3 = *(const short8*)(bbase + 3*4096);
  #pragma unroll
  for (int s=0;s<8;++s){
    short8 na0, na1, nb0, nb1, nb2, nb3;
    if (s < 7){
      na0 = *(const short8*)(wbase + 0*4096 + (s+1)*512);
      na1 = *(const short8*)(wbase + 1*4096 + (s+1)*512);
      nb0 = *(const short8*)(bbase + 0*4096 + (s+1)*512);
      nb1 = *(const short8*)(bbase + 1*4096 + (s+1)*512);
      nb2 = *(const short8*)(bbase + 2*4096 + (s+1)*512);
      nb3 = *(const short8*)(bbase + 3*4096 + (s+1)*512);
    }
    acc[0][0] = __builtin_amdgcn_mfma_f32_16x16x32_bf16(a0, b0, acc[0][0], 0,0,0);
    acc[0][1] = __builtin_amdgcn_mfma_f32_16x16x32_bf16(a0, b1, acc[0][1], 0,0,0);
    acc[0][2] = __builtin_amdgcn_mfma_f32_16x16x32_bf16(a0, b2, acc[0][2], 0,0,0);
    acc[0][3] = __builtin_amdgcn_mfma_f32_16x16x32_bf16(a0, b3, acc[0][3], 0,0,0);
    acc[1][0] = __builtin_amdgcn_mfma_f32_16x16x32_bf16(a1, b0, acc[1][0], 0,0,0);
    acc[1][1] = __builtin_amdgcn_mfma_f32_16x16x32_bf16(a1, b1, acc[1][1], 0,0,0);
    acc[1][2] = __builtin_amdgcn_mfma_f32_16x16x32_bf16(a1, b2, acc[1][2], 0,0,0);
    acc[1][3] = __builtin_amdgcn_mfma_f32_16x16x32_bf16(a1, b3, acc[1][3], 0,0,0);
    if (s < 7){
      a0 = na0; a1 = na1; b0 = nb0; b1 = nb1; b2 = nb2; b3 = nb3;
    }
  }

  float wgt[4];
  #pragma unroll
  for (int n=0;n<4;++n){
    int p = p0 + wn*64 + n*16 + lr;
    wgt[n] = t.wtab ? t.wtab[p] : 1.f;
  }

  float* meanRow = means + (size_t)t.slot*2048 + b*256;
  __syncthreads();   // smean zeroed; cs free

  #pragma unroll
  for (int half=0; half<2; ++half){
    if (wm == half){
      #pragma unroll
      for (int m=0;m<2;++m){
        #pragma unroll
        for (int rg=0;rg<4;++rg){
          int colL = m*16 + g*4 + rg;
          int col  = half*32 + colL;
          float bias = t.bias[co0 + col];
          unsigned short* sp = cs + (size_t)colL*136 + wn*64 + lr;
          float s = 0.f;
          #pragma unroll
          for (int n=0;n<4;++n){
            float v = silu_f(acc[m][n][rg] + bias);
            sp[n*16] = f2bf(v);
            s += v * wgt[n];
          }
          s += __shfl_xor(s, 1);
          s += __shfl_xor(s, 2);
          s += __shfl_xor(s, 4);
          s += __shfl_xor(s, 8);
          if (lr == 0) atomicAdd(&smean[col], s);
        }
      }
    }
    __syncthreads();
    #pragma unroll
    for (int h=0; h<2; ++h){
      int jc = h*256 + tid;
      int colL = jc >> 4, pq = jc & 15;
      uint4 v = *(const uint4*)(cs + (size_t)colL*136 + pq*8);
      unsigned short* op = t.out + ((size_t)(b*256 + co0 + half*32 + colL))*t.HW + p0 + pq*8;
      *(uint4*)op = v;
    }
    __syncthreads();
  }
  if (tid < 64){
    atomicAdd(&meanRow[co0 + tid], smean[tid] * t.norm);
  }
}

// ---------------- fused: attn + weighted-max + 3x3 pool + fea-mean (separable bilinear) ----------------
struct FpT { const unsigned short* uA; const unsigned short* uB; const unsigned short* uUp;
             unsigned short* fea; int iA, iB, iUp, blocks; float norm; int lvl; };
struct FpArgs { FpT t[3]; };

template<int H, int LW, int SLAB, bool HASB, bool HASU, int HUP>
__device__ void fusepool_body(const FpT& t, int bid,
                              const float* __restrict__ means,
                              const float* __restrict__ atw, const float* __restrict__ atb,
                              float* __restrict__ feaMean,
                              float* __restrict__ Vs, float* __restrict__ HR){
  constexpr int W = 1 << LW;
  constexpr int P = W + 2;
  const int tid = threadIdx.x;
  const int bc = bid & 2047, si = bid >> 11;
  const int b = bc >> 8;
  const int r0 = si * SLAB;
  const unsigned short* pA = t.uA + (size_t)bc*H*W;
  const unsigned short* pB = HASB ? t.uB + (size_t)bc*H*W : nullptr;
  const unsigned short* pU = HASU ? t.uUp + (size_t)bc*HUP*HUP : nullptr;

  __shared__ float red4[4][3];
  __shared__ float atnL[3];
  {
    float awv = (tid < 256) ? atw[tid] : 0.f;
    float s0 = means[(size_t)t.iA*2048 + b*256 + tid] * awv;
    float s1 = HASB ? means[(size_t)t.iB*2048 + b*256 + tid] * awv : 0.f;
    float s2 = HASU ? means[(size_t)t.iUp*2048 + b*256 + tid] * awv : 0.f;
    #pragma unroll
    for (int off=32; off; off>>=1){
      s0 += __shfl_down(s0, off);
      if (HASB) s1 += __shfl_down(s1, off);
      if (HASU) s2 += __shfl_down(s2, off);
    }
    int wid = tid >> 6;
    if ((tid & 63) == 0){ red4[wid][0]=s0; red4[wid][1]=s1; red4[wid][2]=s2; }
    __syncthreads();
    if (tid == 0){
      float ab0 = atb[0];
      atnL[0] = hsig_f(fmaxf(red4[0][0]+red4[1][0]+red4[2][0]+red4[3][0] + ab0, 0.f));
      if (HASB) atnL[1] = hsig_f(fmaxf(red4[0][1]+red4[1][1]+red4[2][1]+red4[3][1] + ab0, 0.f));
      if (HASU) atnL[2] = hsig_f(fmaxf(red4[0][2]+red4[1][2]+red4[2][2]+red4[3][2] + ab0, 0.f));
    }
    __syncthreads();
  }
  const float wA = atnL[0];
  const float wB = HASB ? atnL[1] : 0.f;
  const float wU = HASU ? atnL[2] : 0.f;
  const float SC = HASU ? (float)(HUP-1)/(float)(H-1) : 0.f;

  int sy_lo = 0;
  if (HASU){
    int ylo = max(r0 - 1, 0);
    int yhi = min(r0 + SLAB, H - 1);
    sy_lo = (int)(ylo * SC);
    int sy_hi = min((int)(yhi * SC) + 1, HUP - 1);
    int NS = sy_hi - sy_lo + 1;
    for (int i = tid; i < NS * W; i += 256){
      int sy = i >> LW, x = i & (W - 1);
      const unsigned short* src = pU + (size_t)(sy_lo + sy) * HUP;
      float xs = x * SC; int x0 = (int)xs; float fx = xs - x0; int x1 = min(x0 + 1, HUP - 1);
      HR[sy * W + x] = bf2f(src[x0]) * (1.f - fx) + bf2f(src[x1]) * fx;
    }
  }

  for (int r=tid; r<SLAB+2; r+=256){ Vs[r*P] = -INFINITY; Vs[r*P + W+1] = -INFINITY; }
  __syncthreads();

  constexpr int NQ = (SLAB+2)*(W/4);
  for (int q=tid; q<NQ; q+=256){
    int row = q >> (LW-2);
    int xq = (q & ((W/4)-1)) << 2;
    int y = r0 - 1 + row;
    float v0=-INFINITY, v1=-INFINITY, v2=-INFINITY, v3=-INFINITY;
    if (y >= 0 && y < H){
      int ro = y*W + xq;
      ushort4 a4 = *(const ushort4*)(pA + ro);
      v0 = bf2f(a4.x)*wA; v1 = bf2f(a4.y)*wA; v2 = bf2f(a4.z)*wA; v3 = bf2f(a4.w)*wA;
      if (HASB){
        ushort4 b4 = *(const ushort4*)(pB + ro);
        v0 = fmaxf(v0, bf2f(b4.x)*wB); v1 = fmaxf(v1, bf2f(b4.y)*wB);
        v2 = fmaxf(v2, bf2f(b4.z)*wB); v3 = fmaxf(v3, bf2f(b4.w)*wB);
      }
      if (HASU){
        float ys = y*SC; int y0 = (int)ys; float fy = ys - y0; int y1 = min(y0+1, HUP-1);
        float gy = 1.f - fy;
        const float* h0 = HR + (y0 - sy_lo)*W + xq;
        const float* h1 = HR + (y1 - sy_lo)*W + xq;
        float4 ra = *(const float4*)h0;
        float4 rb = *(const float4*)h1;
        v0 = fmaxf(v0, (ra.x*gy + rb.x*fy) * wU);
        v1 = fmaxf(v1, (ra.y*gy + rb.y*fy) * wU);
        v2 = fmaxf(v2, (ra.z*gy + rb.z*fy) * wU);
        v3 = fmaxf(v3, (ra.w*gy + rb.w*fy) * wU);
      }
    }
    float* vr = Vs + row*P + 1 + xq;
    vr[0]=v0; vr[1]=v1; vr[2]=v2; vr[3]=v3;
  }
  __syncthreads();

  float sum = 0.f;
  constexpr int NO = SLAB*(W/4);
  unsigned short* fb = t.fea + (size_t)bc*H*W + r0*W;
  for (int q=tid; q<NO; q+=256){
    int row = q >> (LW-2);
    int x4 = (q & ((W/4)-1)) << 2;
    const float* rp0 = Vs + row*P + x4;
    const float* rp1 = rp0 + P;
    const float* rp2 = rp1 + P;
    float c0,c1,c2,c3,c4,c5, m0,m1,m2,m3;
    c0=rp0[0]; c1=rp0[1]; c2=rp0[2]; c3=rp0[3]; c4=rp0[4]; c5=rp0[5];
    m0 = fmaxf(fmaxf(c0,c1),c2);
    m1 = fmaxf(fmaxf(c1,c2),c3);
    m2 = fmaxf(fmaxf(c2,c3),c4);
    m3 = fmaxf(fmaxf(c3,c4),c5);
    c0=rp1[0]; c1=rp1[1]; c2=rp1[2]; c3=rp1[3]; c4=rp1[4]; c5=rp1[5];
    m0 = fmaxf(m0, fmaxf(fmaxf(c0,c1),c2));
    m1 = fmaxf(m1, fmaxf(fmaxf(c1,c2),c3));
    m2 = fmaxf(m2, fmaxf(fmaxf(c2,c3),c4));
    m3 = fmaxf(m3, fmaxf(fmaxf(c3,c4),c5));
    c0=rp2[0]; c1=rp2[1]; c2=rp2[2]; c3=rp2[3]; c4=rp2[4]; c5=rp2[5];
    m0 = fmaxf(m0, fmaxf(fmaxf(c0,c1),c2));
    m1 = fmaxf(m1, fmaxf(fmaxf(c1,c2),c3));
    m2 = fmaxf(m2, fmaxf(fmaxf(c2,c3),c4));
    m3 = fmaxf(m3, fmaxf(fmaxf(c3,c4),c5));
    ushort4 o; o.x=f2bf(m0); o.y=f2bf(m1); o.z=f2bf(m2); o.w=f2bf(m3);
    *(ushort4*)(fb + row*W + x4) = o;
    sum += m0+m1+m2+m3;
  }
  #pragma unroll
  for (int off=32; off; off>>=1) sum += __shfl_down(sum, off);
  __shared__ float red[4];
  if ((tid & 63) == 0) red[tid >> 6] = sum;
  __syncthreads();
  if (tid == 0)
    atomicAdd(&feaMean[t.lvl*2048 + bc], (red[0]+red[1]+red[2]+red[3]) * t.norm);
}

__global__ __launch_bounds__(256) void fusepool_kernel(FpArgs A,
                                                       const float* __restrict__ means,
                                                       const float* __restrict__ atw,
                                                       const float* __restrict__ atb,
                                                       float* __restrict__ feaMean){
  __shared__ float Vs[34*66];
  __shared__ float HR[18*64];
  int bid = blockIdx.x; int ti = 0;
  while (bid >= A.t[ti].blocks){ bid -= A.t[ti].blocks; ++ti; }
  if (ti == 0)      fusepool_body<64,6,32,false,true,32>(A.t[0], bid, means, atw, atb, feaMean, Vs, HR);
  else if (ti == 1) fusepool_body<32,5,32,true, true,16>(A.t[1], bid, means, atw, atb, feaMean, Vs, HR);
  else              fusepool_body<16,4,16,true,false, 2>(A.t[2], bid, means, atw, atb, feaMean, Vs, HR);
}

// ---------------- DyReLU FC chain ----------------
__global__ __launch_bounds__(256) void fc_kernel(const float* __restrict__ feaMean,
                                                 const float* __restrict__ w1, const float* __restrict__ b1,
                                                 const float* __restrict__ w2, const float* __restrict__ b2,
                                                 float* __restrict__ coef){
  int lb = blockIdx.x;
  const float* m = feaMean + (size_t)lb*CC;
  __shared__ float sm[CC];
  __shared__ float sy[64];
  sm[threadIdx.x] = m[threadIdx.x];
  __syncthreads();
  if (threadIdx.x < 64){
    float s = b1[threadIdx.x];
    const float* wr = w1 + (size_t)threadIdx.x*CC;
    for (int k=0;k<CC;++k) s += wr[k]*sm[k];
    sy[threadIdx.x] = fmaxf(s, 0.f);
  }
  __syncthreads();
  for (int j = threadIdx.x; j < 1024; j += 256){
    float s = b2[j];
    const float* wr = w2 + (size_t)j*64;
    for (int k=0;k<64;++k) s += wr[k]*sy[k];
    float y = hsig_f(s);
    int seg = j >> 8;
    float o;
    if (seg==0)      o = (y-0.5f)*2.f + 1.f;
    else if (seg==1) o = y - 0.5f;
    else if (seg==2) o = (y-0.5f)*2.f;
    else             o = y - 0.5f;
    coef[(size_t)lb*1024 + j] = o;
  }
}

// ---------------- DyReLU apply (8 elems/thread) ----------------
struct ApT { const unsigned short* fea; const float* coefL; float* out; int lhw; int blocks; };
struct ApArgs { ApT t[3]; };

__global__ __launch_bounds__(256) void apply_kernel(ApArgs A){
  int bid = blockIdx.x; int ti = 0;
  while (bid >= A.t[ti].blocks){ bid -= A.t[ti].blocks; ++ti; }
  ApT t = A.t[ti];
  int e0 = bid*2048 + threadIdx.x*8;
  int bc = e0 >> t.lhw;
  int b = bc >> 8, c = bc & 255;
  const float* cf = t.coefL + (size_t)b*1024;
  float a1 = cf[c], bb1 = cf[256+c], a2 = cf[512+c], bb2 = cf[768+c];
  uint4 xv = *(const uint4*)(t.fea + e0);
  float x0 = bf2f((unsigned short)(xv.x & 0xffff)), x1 = bf2f((unsigned short)(xv.x >> 16));
  float x2 = bf2f((unsigned short)(xv.y & 0xffff)), x3 = bf2f((unsigned short)(xv.y >> 16));
  float x4 = bf2f((unsigned short)(xv.z & 0xffff)), x5 = bf2f((unsigned short)(xv.z >> 16));
  float x6 = bf2f((unsigned short)(xv.w & 0xffff)), x7 = bf2f((unsigned short)(xv.w >> 16));
  float4 o0, o1;
  o0.x = fmaxf(x0*a1 + bb1, x0*a2 + bb2);
  o0.y = fmaxf(x1*a1 + bb1, x1*a2 + bb2);
  o0.z = fmaxf(x2*a1 + bb1, x2*a2 + bb2);
  o0.w = fmaxf(x3*a1 + bb1, x3*a2 + bb2);
  o1.x = fmaxf(x4*a1 + bb1, x4*a2 + bb2);
  o1.y = fmaxf(x5*a1 + bb1, x5*a2 + bb2);
  o1.z = fmaxf(x6*a1 + bb1, x6*a2 + bb2);
  o1.w = fmaxf(x7*a1 + bb1, x7*a2 + bb2);
  *(float4*)(t.out + e0) = o0;
  *(float4*)(t.out + e0 + 4) = o1;
}

extern "C" void kernel_launch(void* const* d_in, const int* in_sizes, int n_in,
                              void* d_out, int out_size, void* d_ws, size_t ws_size,
                              hipStream_t stream) {
  const float* x0    = (const float*)d_in[0];
  const float* x1    = (const float*)d_in[1];
  const float* x2    = (const float*)d_in[2];
  const float* dw_w  = (const float*)d_in[3];
  const float* dw_b  = (const float*)d_in[4];
  const float* pw_w  = (const float*)d_in[5];
  const float* pw_b  = (const float*)d_in[6];
  const float* atw   = (const float*)d_in[7];
  const float* atb   = (const float*)d_in[8];
  const float* fc1w  = (const float*)d_in[9];
  const float* fc1b  = (const float*)d_in[10];
  const float* fc2w  = (const float*)d_in[11];
  const float* fc2b  = (const float*)d_in[12];
  float* out = (float*)d_out;

  const size_t A64 = (size_t)BB*CC*64*64;
  const size_t A32 = (size_t)BB*CC*32*32;
  const size_t A16 = (size_t)BB*CC*16*16;

  unsigned short* us = (unsigned short*)d_ws;
  unsigned short* bA = us;
  unsigned short* bB = bA + A64;
  unsigned short* bC = bB + A32;
  unsigned short* bD = bC + A32;
  unsigned short* bE = bD + A32;
  unsigned short* bF = bE + A16;
  unsigned short* bG = bF + A16;
  unsigned short* uA = bG + A16;
  unsigned short* uB = uA + A64;
  unsigned short* uC = uB + A32;
  unsigned short* uD = uC + A32;
  unsigned short* uE = uD + A32;
  unsigned short* uF = uE + A16;
  unsigned short* uG = uF + A16;
  unsigned short* fe0 = uG + A16;
  unsigned short* fe1 = fe0 + A64;
  unsigned short* fe2 = fe1 + A32;
  unsigned short* wbf = fe2 + A16;
  float* fb      = (float*)(wbf + 5*65536);
  float* wtab32  = fb;
  float* wtab16  = wtab32 + 1024;
  float* means   = wtab16 + 256;            // 7*2048 (zeroed by prep blocks)
  float* feaMean = means + 7*2048;          // 3*2048 (zeroed by prep blocks)
  float* attnW   = feaMean + 3*2048;
  float* coef    = attnW + 64;

  const float* W1 = dw_w + 1*CC*9; const float* B1 = dw_b + 1*CC;
  const float* W4 = dw_w + 4*CC*9; const float* B4 = dw_b + 4*CC;
  const float* W5 = dw_w + 5*CC*9; const float* B5 = dw_b + 5*CC;
  const float* W7 = dw_w + 7*CC*9; const float* B7 = dw_b + 7*CC;
  const float* W8 = dw_w + 8*CC*9; const float* B8 = dw_b + 8*CC;

  // 1. merged depthwise (32-ch slabs) + prep
  {
    DwPrepArgs DA;
    DA.g[0] = {x0, W1,B1,bA,  nullptr,nullptr,nullptr,  W5,B5,bD,  1024};
    DA.g[1] = {x1, W1,B1,bB,  W4,B4,bC,                 W8,B8,bG,  512};
    DA.g[2] = {x2, W4,B4,bE,  W7,B7,bF,                 nullptr,nullptr,nullptr, 128};
    DA.pw_w = pw_w; DA.wbf = wbf; DA.wtab32 = wtab32; DA.wtab16 = wtab16; DA.zeros = means;
    dw_kernel<<<1664 + 1365, 256, 0, stream>>>(DA);
  }

  // 2. pointwise 1x1 via MFMA + mean atomics (sw-pipelined)
  {
    PwArgs A;
    A.t[0] = {bA, wbf + 0*65536, pw_b + 1*CC, uA, nullptr, 1.f/4096.f, 4096, 1024, 0};
    A.t[1] = {bB, wbf + 0*65536, pw_b + 1*CC, uB, wtab32,  1.f/4096.f, 1024, 256, 1};
    A.t[2] = {bC, wbf + 1*65536, pw_b + 4*CC, uC, nullptr, 1.f/1024.f, 1024, 256, 2};
    A.t[3] = {bD, wbf + 2*65536, pw_b + 5*CC, uD, nullptr, 1.f/1024.f, 1024, 256, 3};
    A.t[4] = {bE, wbf + 1*65536, pw_b + 4*CC, uE, wtab16,  1.f/1024.f, 256,  64, 4};
    A.t[5] = {bF, wbf + 3*65536, pw_b + 7*CC, uF, nullptr, 1.f/256.f,  256,  64, 5};
    A.t[6] = {bG, wbf + 4*65536, pw_b + 8*CC, uG, nullptr, 1.f/256.f,  256,  64, 6};
    pw_kernel<<<1984, 256, 0, stream>>>(A, means);
  }

  // 3. fused attn + weighted-max + 3x3 pool + fea-mean (separable bilinear)
  {
    FpArgs F;
    F.t[0] = {uA, nullptr, uB,      fe0, 0,-1, 1, 4096, 1.f/4096.f, 0};
    F.t[1] = {uC, uD,      uE,      fe1, 2, 3, 4, 2048, 1.f/1024.f, 1};
    F.t[2] = {uF, uG,      nullptr, fe2, 5, 6,-1, 2048, 1.f/256.f,  2};
    fusepool_kernel<<<8192, 256, 0, stream>>>(F, means, atw, atb, feaMean);
  }

  // 4. DyReLU FC chain
  fc_kernel<<<24, 256, 0, stream>>>(feaMean, fc1w, fc1b, fc2w, fc2b, coef);

  // 5. DyReLU apply (8 elems/thread)
  {
    ApArgs P;
    P.t[0] = {fe0, coef + 0*8192, out,             12, 4096};
    P.t[1] = {fe1, coef + 1*8192, out + A64,       10, 1024};
    P.t[2] = {fe2, coef + 2*8192, out + A64 + A32,  8, 256};
    apply_kernel<<<5376, 256, 0, stream>>>(P);
  }
}

// Round 15
// 113.735 us; speedup vs baseline: 1.0606x; 1.0606x over previous
//
#include <hip/hip_runtime.h>

#define BB 8
#define CC 256

typedef __attribute__((ext_vector_type(8))) short short8;
typedef __attribute__((ext_vector_type(4))) float f32x4;

__device__ __forceinline__ float silu_f(float v){
  float e = exp2f(v * -1.44269504088896340736f);
  return v * __builtin_amdgcn_rcpf(1.f + e);
}
__device__ __forceinline__ float hsig_f(float v){ return fminf(fmaxf(v + 3.f, 0.f), 6.f) * (1.f/6.f); }
__device__ __forceinline__ unsigned short f2bf(float f){
  unsigned int u = __float_as_uint(f);
  unsigned int r = u + 0x7fffu + ((u >> 16) & 1u);
  return (unsigned short)(r >> 16);
}
__device__ __forceinline__ float bf2f(unsigned short u){ return __uint_as_float(((unsigned int)u)<<16); }

// ================= depthwise: merged-input multi-conv, 32-ch slabs (+ prep blocks) =================
struct DwG {
  const float* in;
  const float* w1a; const float* b1a; unsigned short* o1a;
  const float* w1b; const float* b1b; unsigned short* o1b;
  const float* w2;  const float* b2;  unsigned short* o2;
  int blocks;
};
struct DwPrepArgs {
  DwG g[3];
  const float* pw_w; unsigned short* wbf;
  float* wtab32; float* wtab16; float* zeros;
};

template<int C> struct RowT { float v[C+2]; };

template<int C>
__device__ __forceinline__ void loadRow(const float* rp, bool valid, bool hasL, bool hasR, RowT<C>& r){
  if (!valid){
    #pragma unroll
    for (int i=0;i<C+2;++i) r.v[i]=0.f;
    return;
  }
  r.v[0] = hasL ? rp[-1] : 0.f;
  if constexpr (C >= 4){
    #pragma unroll
    for (int q=0;q<C/4;++q){
      float4 f = *(const float4*)(rp + q*4);
      r.v[1+q*4+0]=f.x; r.v[1+q*4+1]=f.y; r.v[1+q*4+2]=f.z; r.v[1+q*4+3]=f.w;
    }
  } else {
    #pragma unroll
    for (int i=0;i<C;++i) r.v[1+i] = rp[i];
  }
  r.v[C+1] = hasR ? rp[C] : 0.f;
}

template<int C>
__device__ __forceinline__ void conv1row(const RowT<C>& ra, const RowT<C>& rb, const RowT<C>& rc,
                                         const float* w9, float bias, unsigned short* dst){
  #pragma unroll
  for (int j=0;j<C;++j){
    float a = bias
      + w9[0]*ra.v[j] + w9[1]*ra.v[j+1] + w9[2]*ra.v[j+2]
      + w9[3]*rb.v[j] + w9[4]*rb.v[j+1] + w9[5]*rb.v[j+2]
      + w9[6]*rc.v[j] + w9[7]*rc.v[j+1] + w9[8]*rc.v[j+2];
    dst[j] = f2bf(silu_f(a));
  }
}

template<int C>
__device__ __forceinline__ void conv1rowS2(const RowT<C>& ra, const RowT<C>& rb, const RowT<C>& rc,
                                           const float* w9, float bias, unsigned short* dst){
  #pragma unroll
  for (int jj=0;jj<C/2;++jj){
    float a = bias
      + w9[0]*ra.v[2*jj] + w9[1]*ra.v[2*jj+1] + w9[2]*ra.v[2*jj+2]
      + w9[3]*rb.v[2*jj] + w9[4]*rb.v[2*jj+1] + w9[5]*rb.v[2*jj+2]
      + w9[6]*rc.v[2*jj] + w9[7]*rc.v[2*jj+1] + w9[8]*rc.v[2*jj+2];
    dst[jj] = f2bf(silu_f(a));
  }
}

// gather LDS (padded [32ch][RO][P]) -> fragment-order global (16B chunks)
template<int LWO, int RO, int P>
__device__ __forceinline__ void writeFrag32(const unsigned short* sbuf, unsigned short* outBase,
                                            int cg, int tid){
  constexpr int WO = 1<<LWO;
  constexpr int total = RO*WO*4;
  constexpr int iters = (total + 255)/256;
  #pragma unroll
  for (int h=0; h<iters; ++h){
    int jc = h*256 + tid;
    if (jc < total){
      int lp = jc & 15, c4 = (jc>>4)&3, pt = jc>>6;
      int pl = pt*16 + lp;
      int rowl = pl >> LWO, col = pl & (WO-1);
      const unsigned short* sp = sbuf + ((size_t)(c4*8)*RO + rowl)*P + col;
      unsigned int e0 = sp[0*RO*P], e1 = sp[1*RO*P], e2 = sp[2*RO*P], e3 = sp[3*RO*P];
      unsigned int e4 = sp[4*RO*P], e5 = sp[5*RO*P], e6 = sp[6*RO*P], e7 = sp[7*RO*P];
      uint4 v;
      v.x = e0 | (e1<<16); v.y = e2 | (e3<<16); v.z = e4 | (e5<<16); v.w = e6 | (e7<<16);
      size_t off = (size_t)pt*4096 + (size_t)cg*512 + c4*128 + lp*8;
      *(uint4*)(outBase + off) = v;
    }
  }
}

template<int LW, int R, int N1, bool S2>
__device__ void dw_group32(const DwG& g, int bid, unsigned short* sm){
  constexpr int W = 1<<LW;
  constexpr int C = W/8;
  constexpr int P1 = W + 4;
  constexpr int P2 = W/2 + 4;
  const int tid = threadIdx.x;
  const int ch = tid >> 3, ct = tid & 7, c0 = ct*C;
  const int cg = bid & 7;
  int rest = bid >> 3;
  const int NR = W / R;
  const int b = rest / NR, rb = rest % NR, r0 = rb * R;

  const float* ip = g.in + ((size_t)b*CC + cg*32 + ch) * (W*W);
  const int chg = cg*32 + ch;
  float w1a[9], w1b[9], w2[9];
  float bs1a = g.b1a[chg], bs1b = 0.f, bs2 = 0.f;
  #pragma unroll
  for (int k=0;k<9;++k) w1a[k] = g.w1a[chg*9+k];
  if (N1==2){
    bs1b = g.b1b[chg];
    #pragma unroll
    for (int k=0;k<9;++k) w1b[k] = g.w1b[chg*9+k];
  }
  if (S2){
    bs2 = g.b2[chg];
    #pragma unroll
    for (int k=0;k<9;++k) w2[k] = g.w2[chg*9+k];
  }

  unsigned short* s1a = sm;
  unsigned short* s1b = sm + (size_t)32*R*P1;
  unsigned short* s2b = sm + (size_t)N1*32*R*P1;

  RowT<C> RA, RB, RC;
  const bool hasL = (c0 > 0), hasR = (c0 + C < W);
  {
    int ry = r0-1; loadRow<C>(ip + ry*W + c0, ry>=0 && ry<W, hasL, hasR, RA);
    ry = r0;       loadRow<C>(ip + ry*W + c0, ry>=0 && ry<W, hasL, hasR, RB);
    ry = r0+1;     loadRow<C>(ip + ry*W + c0, ry>=0 && ry<W, hasL, hasR, RC);
  }
  #pragma unroll
  for (int y=0; y<R; ++y){
    const RowT<C>& ra  = (y%3==0)?RA:((y%3==1)?RB:RC);
    const RowT<C>& rbm = (y%3==0)?RB:((y%3==1)?RC:RA);
    const RowT<C>& rc  = (y%3==0)?RC:((y%3==1)?RA:RB);
    conv1row<C>(ra, rbm, rc, w1a, bs1a, s1a + ((size_t)ch*R + y)*P1 + c0);
    if (N1==2) conv1row<C>(ra, rbm, rc, w1b, bs1b, s1b + ((size_t)ch*R + y)*P1 + c0);
    if (S2 && (y%2==0))
      conv1rowS2<C>(ra, rbm, rc, w2, bs2, s2b + ((size_t)ch*(R/2) + y/2)*P2 + c0/2);
    if (y < R-1){
      RowT<C>& dst = (y%3==0)?RA:((y%3==1)?RB:RC);
      int ry = r0 + y + 2;
      loadRow<C>(ip + ry*W + c0, ry>=0 && ry<W, hasL, hasR, dst);
    }
  }
  __syncthreads();

  {
    unsigned short* ob = g.o1a + ((size_t)b*(W*W) + r0*W)*256;
    writeFrag32<LW, R, P1>(s1a, ob, cg, tid);
  }
  if (N1==2){
    unsigned short* ob = g.o1b + ((size_t)b*(W*W) + r0*W)*256;
    writeFrag32<LW, R, P1>(s1b, ob, cg, tid);
  }
  if (S2){
    unsigned short* ob = g.o2 + ((size_t)b*((W/2)*(W/2)) + (r0/2)*(W/2))*256;
    writeFrag32<LW-1, R/2, P2>(s2b, ob, cg, tid);
  }
}

__device__ float accw(int yi, int Ho, int Hi){
  float sc = (float)(Hi-1)/(float)(Ho-1);
  float a = 0.f;
  for (int yo=0; yo<Ho; ++yo){
    float ys = yo*sc; int y0 = (int)ys; float w = ys - y0; int y1 = min(y0+1, Hi-1);
    if (y0==yi) a += 1.f - w;
    if (y1==yi) a += w;
  }
  return a;
}

__global__ __launch_bounds__(256) void dw_kernel(DwPrepArgs A){
  __shared__ unsigned short smem[11008];
  int bid = blockIdx.x;
  if (bid < 1664){
    int gi = 0;
    while (bid >= A.g[gi].blocks){ bid -= A.g[gi].blocks; ++gi; }
    if (gi == 0)      dw_group32<6,4,1,true >(A.g[0], bid, smem);
    else if (gi == 1) dw_group32<5,4,2,true >(A.g[1], bid, smem);
    else              dw_group32<4,8,2,false>(A.g[2], bid, smem);
    return;
  }
  int idx = (bid - 1664)*256 + threadIdx.x;
  const int T = 5*65536;
  if (idx < T){
    const int widx[5] = {1,4,5,7,8};
    int slot = idx >> 16, r = idx & 65535;
    int ct = r>>12, s=(r>>9)&7, g=(r>>7)&3, lr=(r>>3)&15, e=r&7;
    int co = ct*16+lr, k = s*32+g*8+e;
    A.wbf[idx] = f2bf(A.pw_w[(size_t)widx[slot]*65536 + co*256 + k]);
  } else if (idx < T+1024){
    int p = idx - T; int y=p>>5, x=p&31;
    A.wtab32[p] = accw(y,64,32)*accw(x,64,32);
  } else if (idx < T+1280){
    int p = idx - T - 1024; int y=p>>4, x=p&15;
    A.wtab16[p] = accw(y,32,16)*accw(x,32,16);
  } else if (idx < T+1280+20480){
    A.zeros[idx - T - 1280] = 0.f;
  }
}

// ---------------- pointwise 1x1 via bf16 MFMA (XCD-swizzled blocks) ----------------
struct PwT { const unsigned short* in; const unsigned short* w; const float* bias;
             unsigned short* out; const float* wtab; float norm; int HW; int blocks; int slot; };
struct PwArgs { PwT t[7]; };

__global__ __launch_bounds__(256) void pw_kernel(PwArgs A, float* __restrict__ means){
  __shared__ unsigned short cs[32*136];
  __shared__ float smean[64];
  // XCD-aware swizzle: grid = 1984 = 8*248; consecutive work ids (which share B fragments)
  // land on the SAME XCD's L2 instead of round-robin across all 8.
  int bid = (blockIdx.x & 7) * 248 + (blockIdx.x >> 3);
  int ti = 0;
  while (bid >= A.t[ti].blocks){ bid -= A.t[ti].blocks; ++ti; }
  PwT t = A.t[ti];
  const int nbx = t.HW >> 7;
  const int b  = bid / (nbx*4);
  const int r  = bid % (nbx*4);
  const int co0 = (r & 3) * 64;
  const int p0  = (r >> 2) * 128;
  const int tid = threadIdx.x;
  const int wid = tid >> 6, l = tid & 63;
  const int wm = wid >> 1, wn = wid & 1;
  const int lr = l & 15, g = l >> 4;

  if (tid < 64) smean[tid] = 0.f;

  const unsigned short* wbase = t.w + ((co0 + wm*32) >> 4)*4096 + l*8;
  const unsigned short* bbase = t.in + (size_t)b*t.HW*256 + ((p0 + wn*64) >> 4)*4096 + l*8;

  f32x4 acc[2][4] = {};
  short8 a0 = *(const short8*)(wbase + 0*4096);
  short8 a1 = *(const short8*)(wbase + 1*4096);
  short8 b0 = *(const short8*)(bbase + 0*4096);
  short8 b1 = *(const short8*)(bbase + 1*4096);
  short8 b2 = *(const short8*)(bbase + 2*4096);
  short8 b3 = *(const short8*)(bbase + 3*4096);
  #pragma unroll
  for (int s=0;s<8;++s){
    short8 na0, na1, nb0, nb1, nb2, nb3;
    if (s < 7){
      na0 = *(const short8*)(wbase + 0*4096 + (s+1)*512);
      na1 = *(const short8*)(wbase + 1*4096 + (s+1)*512);
      nb0 = *(const short8*)(bbase + 0*4096 + (s+1)*512);
      nb1 = *(const short8*)(bbase + 1*4096 + (s+1)*512);
      nb2 = *(const short8*)(bbase + 2*4096 + (s+1)*512);
      nb3 = *(const short8*)(bbase + 3*4096 + (s+1)*512);
    }
    acc[0][0] = __builtin_amdgcn_mfma_f32_16x16x32_bf16(a0, b0, acc[0][0], 0,0,0);
    acc[0][1] = __builtin_amdgcn_mfma_f32_16x16x32_bf16(a0, b1, acc[0][1], 0,0,0);
    acc[0][2] = __builtin_amdgcn_mfma_f32_16x16x32_bf16(a0, b2, acc[0][2], 0,0,0);
    acc[0][3] = __builtin_amdgcn_mfma_f32_16x16x32_bf16(a0, b3, acc[0][3], 0,0,0);
    acc[1][0] = __builtin_amdgcn_mfma_f32_16x16x32_bf16(a1, b0, acc[1][0], 0,0,0);
    acc[1][1] = __builtin_amdgcn_mfma_f32_16x16x32_bf16(a1, b1, acc[1][1], 0,0,0);
    acc[1][2] = __builtin_amdgcn_mfma_f32_16x16x32_bf16(a1, b2, acc[1][2], 0,0,0);
    acc[1][3] = __builtin_amdgcn_mfma_f32_16x16x32_bf16(a1, b3, acc[1][3], 0,0,0);
    if (s < 7){
      a0 = na0; a1 = na1; b0 = nb0; b1 = nb1; b2 = nb2; b3 = nb3;
    }
  }

  float wgt[4];
  #pragma unroll
  for (int n=0;n<4;++n){
    int p = p0 + wn*64 + n*16 + lr;
    wgt[n] = t.wtab ? t.wtab[p] : 1.f;
  }

  float* meanRow = means + (size_t)t.slot*2048 + b*256;
  __syncthreads();

  #pragma unroll
  for (int half=0; half<2; ++half){
    if (wm == half){
      #pragma unroll
      for (int m=0;m<2;++m){
        #pragma unroll
        for (int rg=0;rg<4;++rg){
          int colL = m*16 + g*4 + rg;
          int col  = half*32 + colL;
          float bias = t.bias[co0 + col];
          unsigned short* sp = cs + (size_t)colL*136 + wn*64 + lr;
          float s = 0.f;
          #pragma unroll
          for (int n=0;n<4;++n){
            float v = silu_f(acc[m][n][rg] + bias);
            sp[n*16] = f2bf(v);
            s += v * wgt[n];
          }
          s += __shfl_xor(s, 1);
          s += __shfl_xor(s, 2);
          s += __shfl_xor(s, 4);
          s += __shfl_xor(s, 8);
          if (lr == 0) atomicAdd(&smean[col], s);
        }
      }
    }
    __syncthreads();
    #pragma unroll
    for (int h=0; h<2; ++h){
      int jc = h*256 + tid;
      int colL = jc >> 4, pq = jc & 15;
      uint4 v = *(const uint4*)(cs + (size_t)colL*136 + pq*8);
      unsigned short* op = t.out + ((size_t)(b*256 + co0 + half*32 + colL))*t.HW + p0 + pq*8;
      *(uint4*)op = v;
    }
    __syncthreads();
  }
  if (tid < 64){
    atomicAdd(&meanRow[co0 + tid], smean[tid] * t.norm);
  }
}

// ---------------- fused: attn + weighted-max + 3x3 pool + fea-mean (separable bilinear) ----------------
struct FpT { const unsigned short* uA; const unsigned short* uB; const unsigned short* uUp;
             unsigned short* fea; int iA, iB, iUp, blocks; float norm; int lvl; };
struct FpArgs { FpT t[3]; };

template<int H, int LW, int SLAB, bool HASB, bool HASU, int HUP>
__device__ void fusepool_body(const FpT& t, int bid,
                              const float* __restrict__ means,
                              const float* __restrict__ atw, const float* __restrict__ atb,
                              float* __restrict__ feaMean,
                              float* __restrict__ Vs, float* __restrict__ HR){
  constexpr int W = 1 << LW;
  constexpr int P = W + 2;
  const int tid = threadIdx.x;
  const int bc = bid & 2047, si = bid >> 11;
  const int b = bc >> 8;
  const int r0 = si * SLAB;
  const unsigned short* pA = t.uA + (size_t)bc*H*W;
  const unsigned short* pB = HASB ? t.uB + (size_t)bc*H*W : nullptr;
  const unsigned short* pU = HASU ? t.uUp + (size_t)bc*HUP*HUP : nullptr;

  __shared__ float red4[4][3];
  __shared__ float atnL[3];
  {
    float awv = (tid < 256) ? atw[tid] : 0.f;
    float s0 = means[(size_t)t.iA*2048 + b*256 + tid] * awv;
    float s1 = HASB ? means[(size_t)t.iB*2048 + b*256 + tid] * awv : 0.f;
    float s2 = HASU ? means[(size_t)t.iUp*2048 + b*256 + tid] * awv : 0.f;
    #pragma unroll
    for (int off=32; off; off>>=1){
      s0 += __shfl_down(s0, off);
      if (HASB) s1 += __shfl_down(s1, off);
      if (HASU) s2 += __shfl_down(s2, off);
    }
    int wid = tid >> 6;
    if ((tid & 63) == 0){ red4[wid][0]=s0; red4[wid][1]=s1; red4[wid][2]=s2; }
    __syncthreads();
    if (tid == 0){
      float ab0 = atb[0];
      atnL[0] = hsig_f(fmaxf(red4[0][0]+red4[1][0]+red4[2][0]+red4[3][0] + ab0, 0.f));
      if (HASB) atnL[1] = hsig_f(fmaxf(red4[0][1]+red4[1][1]+red4[2][1]+red4[3][1] + ab0, 0.f));
      if (HASU) atnL[2] = hsig_f(fmaxf(red4[0][2]+red4[1][2]+red4[2][2]+red4[3][2] + ab0, 0.f));
    }
    __syncthreads();
  }
  const float wA = atnL[0];
  const float wB = HASB ? atnL[1] : 0.f;
  const float wU = HASU ? atnL[2] : 0.f;
  const float SC = HASU ? (float)(HUP-1)/(float)(H-1) : 0.f;

  int sy_lo = 0;
  if (HASU){
    int ylo = max(r0 - 1, 0);
    int yhi = min(r0 + SLAB, H - 1);
    sy_lo = (int)(ylo * SC);
    int sy_hi = min((int)(yhi * SC) + 1, HUP - 1);
    int NS = sy_hi - sy_lo + 1;
    for (int i = tid; i < NS * W; i += 256){
      int sy = i >> LW, x = i & (W - 1);
      const unsigned short* src = pU + (size_t)(sy_lo + sy) * HUP;
      float xs = x * SC; int x0 = (int)xs; float fx = xs - x0; int x1 = min(x0 + 1, HUP - 1);
      HR[sy * W + x] = bf2f(src[x0]) * (1.f - fx) + bf2f(src[x1]) * fx;
    }
  }

  for (int r=tid; r<SLAB+2; r+=256){ Vs[r*P] = -INFINITY; Vs[r*P + W+1] = -INFINITY; }
  __syncthreads();

  constexpr int NQ = (SLAB+2)*(W/4);
  for (int q=tid; q<NQ; q+=256){
    int row = q >> (LW-2);
    int xq = (q & ((W/4)-1)) << 2;
    int y = r0 - 1 + row;
    float v0=-INFINITY, v1=-INFINITY, v2=-INFINITY, v3=-INFINITY;
    if (y >= 0 && y < H){
      int ro = y*W + xq;
      ushort4 a4 = *(const ushort4*)(pA + ro);
      v0 = bf2f(a4.x)*wA; v1 = bf2f(a4.y)*wA; v2 = bf2f(a4.z)*wA; v3 = bf2f(a4.w)*wA;
      if (HASB){
        ushort4 b4 = *(const ushort4*)(pB + ro);
        v0 = fmaxf(v0, bf2f(b4.x)*wB); v1 = fmaxf(v1, bf2f(b4.y)*wB);
        v2 = fmaxf(v2, bf2f(b4.z)*wB); v3 = fmaxf(v3, bf2f(b4.w)*wB);
      }
      if (HASU){
        float ys = y*SC; int y0 = (int)ys; float fy = ys - y0; int y1 = min(y0+1, HUP-1);
        float gy = 1.f - fy;
        const float* h0 = HR + (y0 - sy_lo)*W + xq;
        const float* h1 = HR + (y1 - sy_lo)*W + xq;
        float4 ra = *(const float4*)h0;
        float4 rb = *(const float4*)h1;
        v0 = fmaxf(v0, (ra.x*gy + rb.x*fy) * wU);
        v1 = fmaxf(v1, (ra.y*gy + rb.y*fy) * wU);
        v2 = fmaxf(v2, (ra.z*gy + rb.z*fy) * wU);
        v3 = fmaxf(v3, (ra.w*gy + rb.w*fy) * wU);
      }
    }
    float* vr = Vs + row*P + 1 + xq;
    vr[0]=v0; vr[1]=v1; vr[2]=v2; vr[3]=v3;
  }
  __syncthreads();

  float sum = 0.f;
  constexpr int NO = SLAB*(W/4);
  unsigned short* fb = t.fea + (size_t)bc*H*W + r0*W;
  for (int q=tid; q<NO; q+=256){
    int row = q >> (LW-2);
    int x4 = (q & ((W/4)-1)) << 2;
    const float* rp0 = Vs + row*P + x4;
    const float* rp1 = rp0 + P;
    const float* rp2 = rp1 + P;
    float c0,c1,c2,c3,c4,c5, m0,m1,m2,m3;
    c0=rp0[0]; c1=rp0[1]; c2=rp0[2]; c3=rp0[3]; c4=rp0[4]; c5=rp0[5];
    m0 = fmaxf(fmaxf(c0,c1),c2);
    m1 = fmaxf(fmaxf(c1,c2),c3);
    m2 = fmaxf(fmaxf(c2,c3),c4);
    m3 = fmaxf(fmaxf(c3,c4),c5);
    c0=rp1[0]; c1=rp1[1]; c2=rp1[2]; c3=rp1[3]; c4=rp1[4]; c5=rp1[5];
    m0 = fmaxf(m0, fmaxf(fmaxf(c0,c1),c2));
    m1 = fmaxf(m1, fmaxf(fmaxf(c1,c2),c3));
    m2 = fmaxf(m2, fmaxf(fmaxf(c2,c3),c4));
    m3 = fmaxf(m3, fmaxf(fmaxf(c3,c4),c5));
    c0=rp2[0]; c1=rp2[1]; c2=rp2[2]; c3=rp2[3]; c4=rp2[4]; c5=rp2[5];
    m0 = fmaxf(m0, fmaxf(fmaxf(c0,c1),c2));
    m1 = fmaxf(m1, fmaxf(fmaxf(c1,c2),c3));
    m2 = fmaxf(m2, fmaxf(fmaxf(c2,c3),c4));
    m3 = fmaxf(m3, fmaxf(fmaxf(c3,c4),c5));
    ushort4 o; o.x=f2bf(m0); o.y=f2bf(m1); o.z=f2bf(m2); o.w=f2bf(m3);
    *(ushort4*)(fb + row*W + x4) = o;
    sum += m0+m1+m2+m3;
  }
  #pragma unroll
  for (int off=32; off; off>>=1) sum += __shfl_down(sum, off);
  __shared__ float red[4];
  if ((tid & 63) == 0) red[tid >> 6] = sum;
  __syncthreads();
  if (tid == 0)
    atomicAdd(&feaMean[t.lvl*2048 + bc], (red[0]+red[1]+red[2]+red[3]) * t.norm);
}

__global__ __launch_bounds__(256) void fusepool_kernel(FpArgs A,
                                                       const float* __restrict__ means,
                                                       const float* __restrict__ atw,
                                                       const float* __restrict__ atb,
                                                       float* __restrict__ feaMean){
  __shared__ float Vs[34*66];
  __shared__ float HR[18*64];
  int bid = blockIdx.x; int ti = 0;
  while (bid >= A.t[ti].blocks){ bid -= A.t[ti].blocks; ++ti; }
  if (ti == 0)      fusepool_body<64,6,32,false,true,32>(A.t[0], bid, means, atw, atb, feaMean, Vs, HR);
  else if (ti == 1) fusepool_body<32,5,32,true, true,16>(A.t[1], bid, means, atw, atb, feaMean, Vs, HR);
  else              fusepool_body<16,4,16,true,false, 2>(A.t[2], bid, means, atw, atb, feaMean, Vs, HR);
}

// ---------------- DyReLU FC chain ----------------
__global__ __launch_bounds__(256) void fc_kernel(const float* __restrict__ feaMean,
                                                 const float* __restrict__ w1, const float* __restrict__ b1,
                                                 const float* __restrict__ w2, const float* __restrict__ b2,
                                                 float* __restrict__ coef){
  int lb = blockIdx.x;
  const float* m = feaMean + (size_t)lb*CC;
  __shared__ float sm[CC];
  __shared__ float sy[64];
  sm[threadIdx.x] = m[threadIdx.x];
  __syncthreads();
  if (threadIdx.x < 64){
    float s = b1[threadIdx.x];
    const float* wr = w1 + (size_t)threadIdx.x*CC;
    for (int k=0;k<CC;++k) s += wr[k]*sm[k];
    sy[threadIdx.x] = fmaxf(s, 0.f);
  }
  __syncthreads();
  for (int j = threadIdx.x; j < 1024; j += 256){
    float s = b2[j];
    const float* wr = w2 + (size_t)j*64;
    for (int k=0;k<64;++k) s += wr[k]*sy[k];
    float y = hsig_f(s);
    int seg = j >> 8;
    float o;
    if (seg==0)      o = (y-0.5f)*2.f + 1.f;
    else if (seg==1) o = y - 0.5f;
    else if (seg==2) o = (y-0.5f)*2.f;
    else             o = y - 0.5f;
    coef[(size_t)lb*1024 + j] = o;
  }
}

// ---------------- DyReLU apply (8 elems/thread) ----------------
struct ApT { const unsigned short* fea; const float* coefL; float* out; int lhw; int blocks; };
struct ApArgs { ApT t[3]; };

__global__ __launch_bounds__(256) void apply_kernel(ApArgs A){
  int bid = blockIdx.x; int ti = 0;
  while (bid >= A.t[ti].blocks){ bid -= A.t[ti].blocks; ++ti; }
  ApT t = A.t[ti];
  int e0 = bid*2048 + threadIdx.x*8;
  int bc = e0 >> t.lhw;
  int b = bc >> 8, c = bc & 255;
  const float* cf = t.coefL + (size_t)b*1024;
  float a1 = cf[c], bb1 = cf[256+c], a2 = cf[512+c], bb2 = cf[768+c];
  uint4 xv = *(const uint4*)(t.fea + e0);
  float x0 = bf2f((unsigned short)(xv.x & 0xffff)), x1 = bf2f((unsigned short)(xv.x >> 16));
  float x2 = bf2f((unsigned short)(xv.y & 0xffff)), x3 = bf2f((unsigned short)(xv.y >> 16));
  float x4 = bf2f((unsigned short)(xv.z & 0xffff)), x5 = bf2f((unsigned short)(xv.z >> 16));
  float x6 = bf2f((unsigned short)(xv.w & 0xffff)), x7 = bf2f((unsigned short)(xv.w >> 16));
  float4 o0, o1;
  o0.x = fmaxf(x0*a1 + bb1, x0*a2 + bb2);
  o0.y = fmaxf(x1*a1 + bb1, x1*a2 + bb2);
  o0.z = fmaxf(x2*a1 + bb1, x2*a2 + bb2);
  o0.w = fmaxf(x3*a1 + bb1, x3*a2 + bb2);
  o1.x = fmaxf(x4*a1 + bb1, x4*a2 + bb2);
  o1.y = fmaxf(x5*a1 + bb1, x5*a2 + bb2);
  o1.z = fmaxf(x6*a1 + bb1, x6*a2 + bb2);
  o1.w = fmaxf(x7*a1 + bb1, x7*a2 + bb2);
  *(float4*)(t.out + e0) = o0;
  *(float4*)(t.out + e0 + 4) = o1;
}

extern "C" void kernel_launch(void* const* d_in, const int* in_sizes, int n_in,
                              void* d_out, int out_size, void* d_ws, size_t ws_size,
                              hipStream_t stream) {
  const float* x0    = (const float*)d_in[0];
  const float* x1    = (const float*)d_in[1];
  const float* x2    = (const float*)d_in[2];
  const float* dw_w  = (const float*)d_in[3];
  const float* dw_b  = (const float*)d_in[4];
  const float* pw_w  = (const float*)d_in[5];
  const float* pw_b  = (const float*)d_in[6];
  const float* atw   = (const float*)d_in[7];
  const float* atb   = (const float*)d_in[8];
  const float* fc1w  = (const float*)d_in[9];
  const float* fc1b  = (const float*)d_in[10];
  const float* fc2w  = (const float*)d_in[11];
  const float* fc2b  = (const float*)d_in[12];
  float* out = (float*)d_out;

  const size_t A64 = (size_t)BB*CC*64*64;
  const size_t A32 = (size_t)BB*CC*32*32;
  const size_t A16 = (size_t)BB*CC*16*16;

  unsigned short* us = (unsigned short*)d_ws;
  unsigned short* bA = us;
  unsigned short* bB = bA + A64;
  unsigned short* bC = bB + A32;
  unsigned short* bD = bC + A32;
  unsigned short* bE = bD + A32;
  unsigned short* bF = bE + A16;
  unsigned short* bG = bF + A16;
  unsigned short* uA = bG + A16;
  unsigned short* uB = uA + A64;
  unsigned short* uC = uB + A32;
  unsigned short* uD = uC + A32;
  unsigned short* uE = uD + A32;
  unsigned short* uF = uE + A16;
  unsigned short* uG = uF + A16;
  unsigned short* fe0 = uG + A16;
  unsigned short* fe1 = fe0 + A64;
  unsigned short* fe2 = fe1 + A32;
  unsigned short* wbf = fe2 + A16;
  float* fb      = (float*)(wbf + 5*65536);
  float* wtab32  = fb;
  float* wtab16  = wtab32 + 1024;
  float* means   = wtab16 + 256;            // 7*2048 (zeroed by prep blocks)
  float* feaMean = means + 7*2048;          // 3*2048 (zeroed by prep blocks)
  float* attnW   = feaMean + 3*2048;
  float* coef    = attnW + 64;

  const float* W1 = dw_w + 1*CC*9; const float* B1 = dw_b + 1*CC;
  const float* W4 = dw_w + 4*CC*9; const float* B4 = dw_b + 4*CC;
  const float* W5 = dw_w + 5*CC*9; const float* B5 = dw_b + 5*CC;
  const float* W7 = dw_w + 7*CC*9; const float* B7 = dw_b + 7*CC;
  const float* W8 = dw_w + 8*CC*9; const float* B8 = dw_b + 8*CC;

  // 1. merged depthwise (32-ch slabs) + prep
  {
    DwPrepArgs DA;
    DA.g[0] = {x0, W1,B1,bA,  nullptr,nullptr,nullptr,  W5,B5,bD,  1024};
    DA.g[1] = {x1, W1,B1,bB,  W4,B4,bC,                 W8,B8,bG,  512};
    DA.g[2] = {x2, W4,B4,bE,  W7,B7,bF,                 nullptr,nullptr,nullptr, 128};
    DA.pw_w = pw_w; DA.wbf = wbf; DA.wtab32 = wtab32; DA.wtab16 = wtab16; DA.zeros = means;
    dw_kernel<<<1664 + 1365, 256, 0, stream>>>(DA);
  }

  // 2. pointwise 1x1 via MFMA + mean atomics (XCD-swizzled)
  {
    PwArgs A;
    A.t[0] = {bA, wbf + 0*65536, pw_b + 1*CC, uA, nullptr, 1.f/4096.f, 4096, 1024, 0};
    A.t[1] = {bB, wbf + 0*65536, pw_b + 1*CC, uB, wtab32,  1.f/4096.f, 1024, 256, 1};
    A.t[2] = {bC, wbf + 1*65536, pw_b + 4*CC, uC, nullptr, 1.f/1024.f, 1024, 256, 2};
    A.t[3] = {bD, wbf + 2*65536, pw_b + 5*CC, uD, nullptr, 1.f/1024.f, 1024, 256, 3};
    A.t[4] = {bE, wbf + 1*65536, pw_b + 4*CC, uE, wtab16,  1.f/1024.f, 256,  64, 4};
    A.t[5] = {bF, wbf + 3*65536, pw_b + 7*CC, uF, nullptr, 1.f/256.f,  256,  64, 5};
    A.t[6] = {bG, wbf + 4*65536, pw_b + 8*CC, uG, nullptr, 1.f/256.f,  256,  64, 6};
    pw_kernel<<<1984, 256, 0, stream>>>(A, means);
  }

  // 3. fused attn + weighted-max + 3x3 pool + fea-mean (separable bilinear)
  {
    FpArgs F;
    F.t[0] = {uA, nullptr, uB,      fe0, 0,-1, 1, 4096, 1.f/4096.f, 0};
    F.t[1] = {uC, uD,      uE,      fe1, 2, 3, 4, 2048, 1.f/1024.f, 1};
    F.t[2] = {uF, uG,      nullptr, fe2, 5, 6,-1, 2048, 1.f/256.f,  2};
    fusepool_kernel<<<8192, 256, 0, stream>>>(F, means, atw, atb, feaMean);
  }

  // 4. DyReLU FC chain
  fc_kernel<<<24, 256, 0, stream>>>(feaMean, fc1w, fc1b, fc2w, fc2b, coef);

  // 5. DyReLU apply (8 elems/thread)
  {
    ApArgs P;
    P.t[0] = {fe0, coef + 0*8192, out,             12, 4096};
    P.t[1] = {fe1, coef + 1*8192, out + A64,       10, 1024};
    P.t[2] = {fe2, coef + 2*8192, out + A64 + A32,  8, 256};
    apply_kernel<<<5376, 256, 0, stream>>>(P);
  }
}